// Round 1
// baseline (233.181 us; speedup 1.0000x reference)
//
#include <hip/hip_runtime.h>
#include <stdint.h>

// WeightsDropout: per row of 4096 f32 (all > 0), drop the 2048 smallest
// (stable tie-break: smaller index dropped first), softmax over survivors.
constexpr int N     = 4096;
constexpr int KSEL  = 2048;          // int(N * 0.5)
constexpr int BLOCK = 256;
constexpr int NW    = BLOCK / 64;    // 4 waves
constexpr int EPT   = N / BLOCK;     // 16 elements / thread
constexpr int EQCAP = 64;            // max tracked duplicates of T (real data: ~1-3)

__global__ __launch_bounds__(BLOCK, 8)
void wdrop_kernel(const float* __restrict__ w, float* __restrict__ out) {
    const int t    = threadIdx.x;
    const int wid  = t >> 6;
    const int lane = t & 63;
    const uint64_t base = (uint64_t)blockIdx.x * (uint64_t)N;

    __shared__ uint32_t red_lo[NW];
    __shared__ uint32_t red_hi[NW];
    __shared__ int      red_i[NW];
    __shared__ float    red_f[NW];
    __shared__ int      eq_n;
    __shared__ int      eq_idx[EQCAP];

    // ---- load 16 elements as 4 coalesced float4s (chunk j = float4 index j*BLOCK + t)
    uint32_t b[EPT];
    const uint4* wf = (const uint4*)(w + base);
#pragma unroll
    for (int j = 0; j < EPT / 4; ++j) {
        uint4 u = wf[j * BLOCK + t];
        b[j * 4 + 0] = u.x; b[j * 4 + 1] = u.y; b[j * 4 + 2] = u.z; b[j * 4 + 3] = u.w;
    }

    // ---- row min/max on bits (positive floats: bit order == value order)
    uint32_t mn = b[0], mx = b[0];
#pragma unroll
    for (int e = 1; e < EPT; ++e) { mn = min(mn, b[e]); mx = max(mx, b[e]); }
#pragma unroll
    for (int off = 32; off > 0; off >>= 1) {
        mn = min(mn, (uint32_t)__shfl_xor((int)mn, off));
        mx = max(mx, (uint32_t)__shfl_xor((int)mx, off));
    }
    if (t == 0) eq_n = 0;
    if (lane == 0) { red_lo[wid] = mn; red_hi[wid] = mx; }
    __syncthreads();
    uint32_t lo = red_lo[0], hi = red_hi[0];
#pragma unroll
    for (int i = 1; i < NW; ++i) { lo = min(lo, red_lo[i]); hi = max(hi, red_hi[i]); }
    const uint32_t mxbits = hi;   // row max (softmax shift; max is always kept)

    // ---- binary search: T = smallest x with count(bits <= x) >= KSEL  (= k-th smallest)
    while (lo < hi) {                       // uniform per block
        const uint32_t mid = lo + ((hi - lo) >> 1);
        int cnt = 0;
#pragma unroll
        for (int e = 0; e < EPT; ++e)
            cnt += __popcll(__ballot(b[e] <= mid));   // per-wave count, scalar pipe
        __syncthreads();                    // previous iteration's red_i reads done
        if (lane == 0) red_i[wid] = cnt;
        __syncthreads();
        int c = 0;
#pragma unroll
        for (int i = 0; i < NW; ++i) c += red_i[i];
        if (c >= KSEL) hi = mid; else lo = mid + 1;
    }
    const uint32_t T = lo;

    // ---- c_lt = count strictly below T
    int cnt = 0;
#pragma unroll
    for (int e = 0; e < EPT; ++e)
        cnt += __popcll(__ballot(b[e] < T));
    __syncthreads();
    if (lane == 0) red_i[wid] = cnt;
    __syncthreads();
    int c_lt = 0;
#pragma unroll
    for (int i = 0; i < NW; ++i) c_lt += red_i[i];
    const int n_drop_eq = KSEL - c_lt;      // >= 1: equals-to-T with smallest indices drop

    // ---- collect linear indices of elements equal to T (ties are rare)
#pragma unroll
    for (int e = 0; e < EPT; ++e) {
        if (b[e] == T) {
            int slot = atomicAdd(&eq_n, 1);
            if (slot < EQCAP) eq_idx[slot] = ((e >> 2) * BLOCK + t) * 4 + (e & 3);
        }
    }
    __syncthreads();
    const int ne = min(eq_n, EQCAP);

    // ---- keep decision + exp (overwrite b[] with exp bits), partial sum
    const float m = __uint_as_float(mxbits);
    float s = 0.0f;
#pragma unroll
    for (int e = 0; e < EPT; ++e) {
        bool keep = (b[e] > T);
        if (b[e] == T) {
            const int idx = ((e >> 2) * BLOCK + t) * 4 + (e & 3);
            int p = 0;
            for (int q = 0; q < ne; ++q) p += (eq_idx[q] < idx);
            keep = (p >= n_drop_eq);        // stable argsort: smallest indices dropped
        }
        const float ev = keep ? __expf(__uint_as_float(b[e]) - m) : 0.0f;
        b[e] = __float_as_uint(ev);
        s += ev;
    }
#pragma unroll
    for (int off = 32; off > 0; off >>= 1) s += __shfl_xor(s, off);
    __syncthreads();                         // eq_idx / red_i reads done
    if (lane == 0) red_f[wid] = s;
    __syncthreads();
    float tot = 0.0f;
#pragma unroll
    for (int i = 0; i < NW; ++i) tot += red_f[i];
    const float inv = 1.0f / tot;

    // ---- scale + coalesced float4 store
    uint4* of = (uint4*)(out + base);
#pragma unroll
    for (int j = 0; j < EPT / 4; ++j) {
        float4 o;
        o.x = __uint_as_float(b[j * 4 + 0]) * inv;
        o.y = __uint_as_float(b[j * 4 + 1]) * inv;
        o.z = __uint_as_float(b[j * 4 + 2]) * inv;
        o.w = __uint_as_float(b[j * 4 + 3]) * inv;
        ((float4*)of)[j * BLOCK + t] = o;
    }
}

extern "C" void kernel_launch(void* const* d_in, const int* in_sizes, int n_in,
                              void* d_out, int out_size, void* d_ws, size_t ws_size,
                              hipStream_t stream) {
    const float* w = (const float*)d_in[0];
    float* out = (float*)d_out;
    const int rows = in_sizes[0] / N;       // 8192 rows of 4096
    wdrop_kernel<<<rows, BLOCK, 0, stream>>>(w, out);
}